// Round 1
// baseline (18.164 us; speedup 1.0000x reference)
//
#include <hip/hip_runtime.h>
#include <math.h>

// Problem constants (from reference): B=32, N1=N2=64, D1=D2=512, DG=256, DF=256.
// Algebraic collapse: out[b] = sigmoid( m[b] . w + c )
//   m[b] = concat(mean_i O1[b,i,:], mean_j O2[b,j,:])   (1024 floats per batch)
//   v    = Wf1 @ Wf2                                    (256)
//   w    = Wg @ v                                       (1024)
//   c    = bg.v + bf1.Wf2 + bf2                         (scalar)

#define BATCH 32
#define NOBJ  64
#define DHALF 512
#define DCAT  1024
#define DG    256
#define DF    256

// ws layout (float offsets)
#define M_OFF 0                   // 32*1024 = 32768 floats
#define V_OFF (BATCH * DCAT)      // 256 floats
#define C_OFF (V_OFF + DG)        // 1 float
#define W_OFF (C_OFF + 8)         // 1024 floats (padded for alignment)

// Kernel 1: blocks 0..63 compute column means of O1/O2 (float2 per thread,
// 64 rows each); block 64 computes v = Wf1@Wf2 and the scalar c.
__global__ __launch_bounds__(256) void k_means_v(
    const float* __restrict__ O1, const float* __restrict__ O2,
    const float* __restrict__ Wf1, const float* __restrict__ bf1,
    const float* __restrict__ Wf2, const float* __restrict__ bf2,
    const float* __restrict__ bg, float* __restrict__ ws)
{
    __shared__ float wf2s[DF];
    __shared__ float red[4];
    const int tid = threadIdx.x;

    if (blockIdx.x < 64) {
        // 64 blocks * 256 threads = 16384 threads; each owns one float2 column
        // (2 of the 1024 concat dims) of one batch, summed over 64 objects.
        int g2 = blockIdx.x * 256 + tid;      // 0..16383
        int b  = g2 >> 9;                     // batch
        int c2 = g2 & 511;                    // float2 column within concat dim
        const float* src = (c2 < 256)
            ? (O1 + (size_t)b * NOBJ * DHALF + 2 * c2)
            : (O2 + (size_t)b * NOBJ * DHALF + 2 * (c2 - 256));
        float sx = 0.f, sy = 0.f;
        #pragma unroll
        for (int n = 0; n < NOBJ; ++n) {
            float2 t = *reinterpret_cast<const float2*>(src + n * DHALF);
            sx += t.x; sy += t.y;
        }
        float2 r;
        r.x = sx * (1.0f / 64.0f);
        r.y = sy * (1.0f / 64.0f);
        *reinterpret_cast<float2*>(ws + M_OFF + 2 * g2) = r;
    } else {
        // v[k] = sum_j Wf1[k,j] * Wf2[j];  c = bg.v + bf1.Wf2 + bf2
        wf2s[tid] = Wf2[tid];
        __syncthreads();
        const float4* w4 = reinterpret_cast<const float4*>(Wf1 + (size_t)tid * DF);
        float v = 0.f;
        #pragma unroll
        for (int j4 = 0; j4 < DF / 4; ++j4) {
            float4 w = w4[j4];
            v += w.x * wf2s[j4 * 4 + 0] + w.y * wf2s[j4 * 4 + 1]
               + w.z * wf2s[j4 * 4 + 2] + w.w * wf2s[j4 * 4 + 3];
        }
        ws[V_OFF + tid] = v;
        float p = bg[tid] * v + bf1[tid] * wf2s[tid];
        #pragma unroll
        for (int off = 32; off >= 1; off >>= 1) p += __shfl_down(p, off, 64);
        if ((tid & 63) == 0) red[tid >> 6] = p;
        __syncthreads();
        if (tid == 0) ws[C_OFF] = red[0] + red[1] + red[2] + red[3] + bf2[0];
    }
}

// Kernel 2: w[d] = sum_k Wg[d,k] * v[k].  64 blocks * 256 threads.
// Block owns 16 rows d; 16 threads per row, each reads 16 contiguous floats
// (4x float4, fully coalesced across the wave), then shfl-reduce width 16.
__global__ __launch_bounds__(256) void k_w(
    const float* __restrict__ Wg, float* __restrict__ ws)
{
    __shared__ float vs[DG];
    const int tid = threadIdx.x;
    vs[tid] = ws[V_OFF + tid];
    __syncthreads();
    int dl = tid >> 4;                       // 0..15 row within block
    int p  = tid & 15;                       // 0..15 k-chunk
    int d  = blockIdx.x * 16 + dl;           // 0..1023
    const float4* g4 = reinterpret_cast<const float4*>(Wg + (size_t)d * DG + p * 16);
    float s = 0.f;
    #pragma unroll
    for (int i = 0; i < 4; ++i) {
        float4 w = g4[i];
        int k = p * 16 + i * 4;
        s += w.x * vs[k] + w.y * vs[k + 1] + w.z * vs[k + 2] + w.w * vs[k + 3];
    }
    #pragma unroll
    for (int off = 8; off >= 1; off >>= 1) s += __shfl_down(s, off, 16);
    if (p == 0) ws[W_OFF + d] = s;
}

// Kernel 3: out[b] = sigmoid( m[b].w + c ).  32 blocks * 256 threads.
__global__ __launch_bounds__(256) void k_out(
    const float* __restrict__ ws, float* __restrict__ out)
{
    __shared__ float red[4];
    const int b = blockIdx.x;
    const int tid = threadIdx.x;
    const float* m = ws + M_OFF + (size_t)b * DCAT;
    const float* w = ws + W_OFF;
    float s = 0.f;
    #pragma unroll
    for (int i = 0; i < 4; ++i) {
        int d = i * 256 + tid;
        s += m[d] * w[d];
    }
    #pragma unroll
    for (int off = 32; off >= 1; off >>= 1) s += __shfl_down(s, off, 64);
    if ((tid & 63) == 0) red[tid >> 6] = s;
    __syncthreads();
    if (tid == 0) {
        float t = red[0] + red[1] + red[2] + red[3] + ws[C_OFF];
        out[b] = 1.0f / (1.0f + expf(-t));
    }
}

extern "C" void kernel_launch(void* const* d_in, const int* in_sizes, int n_in,
                              void* d_out, int out_size, void* d_ws, size_t ws_size,
                              hipStream_t stream) {
    const float* O1  = (const float*)d_in[0];
    const float* O2  = (const float*)d_in[1];
    const float* Wg  = (const float*)d_in[2];
    const float* bg  = (const float*)d_in[3];
    const float* Wf1 = (const float*)d_in[4];
    const float* bf1 = (const float*)d_in[5];
    const float* Wf2 = (const float*)d_in[6];
    const float* bf2 = (const float*)d_in[7];
    float* ws  = (float*)d_ws;
    float* out = (float*)d_out;

    hipLaunchKernelGGL(k_means_v, dim3(65), dim3(256), 0, stream,
                       O1, O2, Wf1, bf1, Wf2, bf2, bg, ws);
    hipLaunchKernelGGL(k_w, dim3(64), dim3(256), 0, stream, Wg, ws);
    hipLaunchKernelGGL(k_out, dim3(32), dim3(256), 0, stream, ws, out);
}